// Round 9
// baseline (574.555 us; speedup 1.0000x reference)
//
#include <hip/hip_runtime.h>
#include <stdint.h>

typedef unsigned short u16;
typedef __bf16 bf8 __attribute__((ext_vector_type(8)));
typedef float f32x4 __attribute__((ext_vector_type(4)));

#define SEQ 2048
#define HIDDEN 4096
#define DQKV 6144   // 48 heads * 128
#define HD 128

// async global->LDS, 16B/lane. LDS dest is wave-uniform base + lane*16 (m104/m108);
// all staging layouts below are laid out so lane l's element lands at base + l*16B.
#define GLOAD_LDS16(g, l)                                                            \
    __builtin_amdgcn_global_load_lds((const __attribute__((address_space(1))) void*)(g), \
                                     (__attribute__((address_space(3))) void*)(l), 16, 0, 0)

__device__ __forceinline__ u16 f2bf(float f) {
    union { float f; unsigned u; } v{f};
    unsigned r = (v.u + 0x7fff + ((v.u >> 16) & 1)) >> 16;
    return (u16)r;
}
__device__ __forceinline__ float bf2f(u16 b) {
    union { unsigned u; float f; } v;
    v.u = ((unsigned)b) << 16;
    return v.f;
}

// ---------------- pre-pass kernels ----------------

__global__ void convert_bf16_kernel(const float* __restrict__ in, u16* __restrict__ out) {
    int i = (blockIdx.x * 256 + threadIdx.x) * 4;
    float4 v = *(const float4*)(in + i);
    u16 o[4] = {f2bf(v.x), f2bf(v.y), f2bf(v.z), f2bf(v.w)};
    *(uint2*)(out + i) = *(uint2*)o;
}

// in fp32 [K][N] -> out bf16 [N][K]
__global__ void transpose_w_kernel(const float* __restrict__ in, u16* __restrict__ out, int K, int N) {
    __shared__ u16 tile[64][65];
    int tn = N >> 6;
    int bk = blockIdx.x / tn, bn = blockIdx.x % tn;
    int k0 = bk * 64, n0 = bn * 64;
    int c = threadIdx.x & 63, r0 = threadIdx.x >> 6;
#pragma unroll
    for (int r = r0; r < 64; r += 4)
        tile[r][c] = f2bf(in[(size_t)(k0 + r) * N + n0 + c]);
    __syncthreads();
#pragma unroll
    for (int r = r0; r < 64; r += 4)
        out[(size_t)(n0 + r) * K + k0 + c] = tile[c][r];
}

// RoPE in-place on Q/K heads (0..39) of xqkv [2048][6144]
__global__ void rope_kernel(u16* __restrict__ x) {
    const int row = blockIdx.x / 10, hg = blockIdx.x % 10;
    const int head = hg * 4 + (threadIdx.x >> 6), j = threadIdx.x & 63;
    u16* p = x + (size_t)row * DQKV + head * HD + j;
    float x1 = bf2f(p[0]), x2 = bf2f(p[64]);
    float inv = exp2f(-(float)j * 0.20762050593045952f); // log2(10000)/64
    float s, c;
    sincosf((float)row * inv, &s, &c);
    p[0] = f2bf(x1 * c - x2 * s);
    p[64] = f2bf(x1 * s + x2 * c);
}

// V heads (40..47) of xqkv [2048][6144] -> VT [8][128][2048]
__global__ void transpose_v_kernel(const u16* __restrict__ xqkv, u16* __restrict__ vt) {
    __shared__ u16 tile[64][65];
    int h = blockIdx.x >> 6;
    int t = blockIdx.x & 63;
    int s0 = (t >> 1) * 64, d0 = (t & 1) * 64;
    int c = threadIdx.x & 63, r0 = threadIdx.x >> 6;
    const u16* src = xqkv + (40 + h) * HD + d0;
#pragma unroll
    for (int r = r0; r < 64; r += 4)
        tile[r][c] = src[(size_t)(s0 + r) * DQKV + c];
    __syncthreads();
    u16* dst = vt + ((size_t)h * HD + d0) * SEQ + s0;
#pragma unroll
    for (int r = r0; r < 64; r += 4)
        dst[(size_t)r * SEQ + c] = tile[c][r];
}

// ---------------- GEMM: C[M][*] = A[M][4096] * BT[N][4096]^T ----------------
// m201 geometry: 256x256 tile, BK=64, 8 waves 2Mx4N, wave tile 128x64 =
// 8 m-frags x 4 n-frags. Frag reads/MFMA = (8+4)/(8*4) = 0.375 < 4.85/12 ~=
// 0.40 -> MFMA-bound. All prior variants (0.417-0.458) were LDS-read-bound,
// which is why five schedule changes all tied at ~950 TF.
// Per K-tile, quadrant phases (m-half, n-half): (00)->(01)->(11)->(10), frag
// reads 12/4/8/0 (A halves read once, B halves held across the tile).
// Phase = {stage-issue || ds_reads -> barrier -> lgkmcnt(0) -> setprio(1) ->
// 16 MFMA -> setprio(0) -> barrier}; p3 has no reads (regs live) so only the
// boundary barrier. Staging of tile t+2 goes into buf[cur] regions as they
// die: A0,A2 at p1 (read p0 only), B0..B3 at p2 (read p0/p1), A1,A3 at p3
// (read p2). Boundary: counted vmcnt(8) drains exactly t+1's 8 loads, leaves
// t+2's 8 in flight (T4; vmcnt(0) only at t=NT-2).
// Swizzle (T2, zero-conflict-verified R2): logical (r,c16B) at phys c^(r&7),
// via pre-permuted gload source col (rule #21); all frag rows have row&7 ==
// l15&7 (m/n-half offsets are multiples of 8 frags... of 64 rows).
// Grids: MODE0 8x24=192 blocks, MODE1 8x16=128 (75%/50% CU fill - accepted:
// per-block rate predicted +60%). T1 XCD chunking adapted per grid.
template <int MODE>  // MODE 0: N=6144, bf16 out. MODE 1: N=4096, f32 out.
__global__ __launch_bounds__(512, 2) void gemm256_kernel(const u16* __restrict__ A,
                                                         const u16* __restrict__ BT,
                                                         u16* __restrict__ Cbf,
                                                         float* __restrict__ Cf) {
    constexpr int CSTR = (MODE == 0) ? DQKV : HIDDEN;
    constexpr int NT = 64;               // K / 64
    __shared__ __align__(16) u16 lds[2][32768];   // [buf][A 256x64 | B 256x64]

    const int tid = threadIdx.x;
    const int w = tid >> 6, l = tid & 63, l15 = l & 15, q4 = l >> 4;
    const int wm = w >> 2, wn = w & 3;

    // T1: XCD-aware chunking (xcd = blockIdx%8 round-robin assumption).
    const int xcd = blockIdx.x & 7, wi = blockIdx.x >> 3;
    const int xr = xcd >> 2, xc = xcd & 3;
    int bm, bn;
    if constexpr (MODE == 0) { bm = xr * 4 + wi / 6; bn = xc * 6 + wi % 6; }   // 8x24
    else                     { bm = xr * 4 + wi / 4; bn = xc * 4 + wi % 4; }   // 8x16

    // staging: thread tid fills phys bytes [line*8192 + tid*16, +16) of a region
    // = logical row line*64 + tid/8, col ((tid&7)^((tid>>3)&7))*16 (swizzled src)
    const int srow = tid >> 3;
    const int scol = ((tid & 7) ^ ((tid >> 3) & 7)) << 4;
    const char* spA[4];
    const char* spB[4];
#pragma unroll
    for (int L = 0; L < 4; ++L) {
        spA[L] = (const char*)(A + (size_t)(bm * 256 + L * 64 + srow) * 4096) + scol;
        spB[L] = (const char*)(BT + (size_t)(bn * 256 + L * 64 + srow) * 4096) + scol;
    }

#define STG_A(L, tt, b) GLOAD_LDS16(spA[L] + (size_t)(tt) * 128, &lds[b][(L) * 4096 + w * 512])
#define STG_B(L, tt, b) GLOAD_LDS16(spB[L] + (size_t)(tt) * 128, &lds[b][16384 + (L) * 4096 + w * 512])

    // prologue: stage tiles 0 and 1; vmcnt(8) drains tile 0, tile 1 in flight
#pragma unroll
    for (int L = 0; L < 4; ++L) { STG_A(L, 0, 0); STG_B(L, 0, 0); }
#pragma unroll
    for (int L = 0; L < 4; ++L) { STG_A(L, 1, 1); STG_B(L, 1, 1); }
    asm volatile("s_waitcnt vmcnt(8)" ::: "memory");
    asm volatile("s_barrier" ::: "memory");

    // read-side swizzle (zero-conflict-verified): frag row&7 == l15&7
    const int c0x = (q4 * 16) ^ ((l15 & 7) << 4);
    const int c1x = c0x ^ 64;

    f32x4 acc[8][4] = {};   // [mh*4+mf][nh*2+nf]

#pragma unroll 1
    for (int t = 0; t < NT; ++t) {
        const int cur = t & 1;
        const char* ldsA = (const char*)&lds[cur][0];
        const char* ldsB = ldsA + 32768;   // bytes
        bf8 a[4][2], b0[2][2], b1[2][2];

        // ---- p0: read A m-half0 (8) + B n-half0 (4); mfma quadrant (0,0)
#pragma unroll
        for (int mf = 0; mf < 4; ++mf) {
            const char* rp = ldsA + (wm * 128 + mf * 16 + l15) * 128;
            a[mf][0] = *(const bf8*)(rp + c0x);
            a[mf][1] = *(const bf8*)(rp + c1x);
        }
#pragma unroll
        for (int nf = 0; nf < 2; ++nf) {
            const char* rp = ldsB + (wn * 64 + nf * 16 + l15) * 128;
            b0[nf][0] = *(const bf8*)(rp + c0x);
            b0[nf][1] = *(const bf8*)(rp + c1x);
        }
        asm volatile("s_barrier" ::: "memory");
        asm volatile("s_waitcnt lgkmcnt(0)" ::: "memory");
        __builtin_amdgcn_s_setprio(1);
#pragma unroll
        for (int mf = 0; mf < 4; ++mf)
#pragma unroll
            for (int nf = 0; nf < 2; ++nf)
#pragma unroll
                for (int ks = 0; ks < 2; ++ks)
                    acc[mf][nf] = __builtin_amdgcn_mfma_f32_16x16x32_bf16(
                        a[mf][ks], b0[nf][ks], acc[mf][nf], 0, 0, 0);
        __builtin_amdgcn_s_setprio(0);
        asm volatile("s_barrier" ::: "memory");

        // ---- p1: stage A0,A2 of t+2 (dead after p0); read B n-half1 (4);
        //          mfma quadrant (0,1)
        if (t < NT - 2) { STG_A(0, t + 2, cur); STG_A(2, t + 2, cur); }
#pragma unroll
        for (int nf = 0; nf < 2; ++nf) {
            const char* rp = ldsB + (wn * 64 + 32 + nf * 16 + l15) * 128;
            b1[nf][0] = *(const bf8*)(rp + c0x);
            b1[nf][1] = *(const bf8*)(rp + c1x);
        }
        asm volatile("s_barrier" ::: "memory");
        asm volatile("s_waitcnt lgkmcnt(0)" ::: "memory");
        __builtin_amdgcn_s_setprio(1);
#pragma unroll
        for (int mf = 0; mf < 4; ++mf)
#pragma unroll
            for (int nf = 0; nf < 2; ++nf)
#pragma unroll
                for (int ks = 0; ks < 2; ++ks)
                    acc[mf][2 + nf] = __builtin_amdgcn_mfma_f32_16x16x32_bf16(
                        a[mf][ks], b1[nf][ks], acc[mf][2 + nf], 0, 0, 0);
        __builtin_amdgcn_s_setprio(0);
        asm volatile("s_barrier" ::: "memory");

        // ---- p2: stage B0..B3 of t+2 (dead after p1); read A m-half1 (8);
        //          mfma quadrant (1,1)
        if (t < NT - 2) {
            STG_B(0, t + 2, cur); STG_B(1, t + 2, cur);
            STG_B(2, t + 2, cur); STG_B(3, t + 2, cur);
        }
#pragma unroll
        for (int mf = 0; mf < 4; ++mf) {
            const char* rp = ldsA + (wm * 128 + 64 + mf * 16 + l15) * 128;
            a[mf][0] = *(const bf8*)(rp + c0x);
            a[mf][1] = *(const bf8*)(rp + c1x);
        }
        asm volatile("s_barrier" ::: "memory");
        asm volatile("s_waitcnt lgkmcnt(0)" ::: "memory");
        __builtin_amdgcn_s_setprio(1);
#pragma unroll
        for (int mf = 0; mf < 4; ++mf)
#pragma unroll
            for (int nf = 0; nf < 2; ++nf)
#pragma unroll
                for (int ks = 0; ks < 2; ++ks)
                    acc[4 + mf][2 + nf] = __builtin_amdgcn_mfma_f32_16x16x32_bf16(
                        a[mf][ks], b1[nf][ks], acc[4 + mf][2 + nf], 0, 0, 0);
        __builtin_amdgcn_s_setprio(0);
        asm volatile("s_barrier" ::: "memory");

        // ---- p3: stage A1,A3 of t+2 (dead after p2); no reads (a, b0 live);
        //          mfma quadrant (1,0)
        if (t < NT - 2) { STG_A(1, t + 2, cur); STG_A(3, t + 2, cur); }
        __builtin_amdgcn_s_setprio(1);
#pragma unroll
        for (int mf = 0; mf < 4; ++mf)
#pragma unroll
            for (int nf = 0; nf < 2; ++nf)
#pragma unroll
                for (int ks = 0; ks < 2; ++ks)
                    acc[4 + mf][nf] = __builtin_amdgcn_mfma_f32_16x16x32_bf16(
                        a[mf][ks], b0[nf][ks], acc[4 + mf][nf], 0, 0, 0);
        __builtin_amdgcn_s_setprio(0);

        // ---- boundary: counted vmcnt (drains t+1 exactly; t+2 in flight)
        if (t < NT - 2) {
            asm volatile("s_waitcnt vmcnt(8)" ::: "memory");
        } else if (t == NT - 2) {
            asm volatile("s_waitcnt vmcnt(0)" ::: "memory");
        }
        asm volatile("s_barrier" ::: "memory");
    }
#undef STG_A
#undef STG_B

    const int rowb = bm * 256 + wm * 128;
    const int colb = bn * 256 + wn * 64;
#pragma unroll
    for (int mh = 0; mh < 2; ++mh)
#pragma unroll
        for (int mf = 0; mf < 4; ++mf)
#pragma unroll
            for (int nh = 0; nh < 2; ++nh)
#pragma unroll
                for (int nf = 0; nf < 2; ++nf)
#pragma unroll
                    for (int r = 0; r < 4; ++r) {
                        const int row = rowb + mh * 64 + mf * 16 + q4 * 4 + r;
                        const int col = colb + nh * 32 + nf * 16 + l15;
                        const float v = acc[mh * 4 + mf][nh * 2 + nf][r];
                        if constexpr (MODE == 0)
                            Cbf[(size_t)row * CSTR + col] = f2bf(v);
                        else
                            Cf[(size_t)row * CSTR + col] = v;
                    }
}

// ---------------- flash attention ----------------
// grid: 512 = 16 q-tiles * 32 heads. block 256 = 4 waves, each wave owns 32 Q rows.
// No running max (scores bounded), unnormalized p=exp2(s*cs), per-lane row-sum,
// one shuffle-reduce + normalize at the end. K/V in GEMM-shaped zero-conflict
// swizzled LDS sub-tiles (R7; conflict fix measured neutral but kept).
#define PSTR 72   // P row stride in shorts: 64 cols + 8 pad (2-way alias = free)
__global__ __launch_bounds__(256) void attn_kernel(const u16* __restrict__ xqkv,
                                                   const u16* __restrict__ vt,
                                                   u16* __restrict__ aw) {
    __shared__ __align__(16) u16 sm[16384 + 128 * PSTR];
    const int tid = threadIdx.x, w = tid >> 6, l = tid & 63, l15 = l & 15, q4 = l >> 4;
    const int qh = blockIdx.x & 31;
    const int qslot = blockIdx.x >> 5;
    // complementary pairing: blocks b and b+256 get qt summing to 15 (tail balance)
    const int qt = (qslot < 8) ? qslot : 23 - qslot;
    const int kh = qh >> 2;

    { // stage Q tile: [ks=w][row 128][32], async (one-time; layout legacy)
        const u16* gq = xqkv + (size_t)(qt * 128 + (l >> 2)) * DQKV + qh * HD + w * 32 + (l & 3) * 8;
#pragma unroll
        for (int i = 0; i < 8; ++i)
            GLOAD_LDS16(gq + (size_t)i * 16 * DQKV, &sm[w * 4096 + i * 512]);
    }
    __syncthreads();
    bf8 qf[4][2];
#pragma unroll
    for (int ks = 0; ks < 4; ++ks)
#pragma unroll
        for (int mt = 0; mt < 2; ++mt)
            qf[ks][mt] = *(const bf8*)&sm[ks * 4096 + (w * 32 + mt * 16 + l15) * 32 + q4 * 8];
    __syncthreads();

    f32x4 O[2][8] = {};
    float plrow[2][4] = {};   // per-lane unnormalized row-sum partials

    u16* ldsK = sm;           // [2][64][64] shorts
    u16* ldsV = sm + 8192;    // [128][64] shorts
    u16* ldsP = sm + 16384;
    const int nkt = 2 * qt + 2;
    const float cs = 0.12751744f; // (1/sqrt(128)) * log2(e)

    // staging source swizzle (GEMM-verified): lane l covers phys row-in-group
    // l>>3, slot l&7 -> loads logical col ((l&7)^(l>>3))*8 elems
    const int sr8 = l >> 3;
    const int sc8 = (l & 7) ^ sr8;
    // K: wave w stages d-half (w&1), seq rows (w>>1)*32..+32
    const u16* gk_base = xqkv + (size_t)((w >> 1) * 32 + sr8) * DQKV + (32 + kh) * HD + (w & 1) * 64 + sc8 * 8;
    u16* ldsK_dst = ldsK + (w & 1) * 4096 + (w >> 1) * 2048;
    // V: wave w stages d-rows w*32..+32 (cols = seq kt*64..+64)
    const u16* gv_base = vt + ((size_t)kh * HD + w * 32 + sr8) * SEQ + sc8 * 8;
    u16* ldsV_dst = ldsV + w * 2048;

    const int cswz = (q4 ^ (l15 & 7)) << 4;   // read-side swizzled byte col
    const char* Kb = (const char*)ldsK;
    const char* Vb = (const char*)ldsV;

    for (int kt = 0; kt < nkt; ++kt) {
        { // stage K tile [64 seq][128 d] as 2 GEMM-shaped sub-tiles
            const u16* gk = gk_base + (size_t)(kt * 64) * DQKV;
#pragma unroll
            for (int i = 0; i < 4; ++i)
                GLOAD_LDS16(gk + (size_t)i * 8 * DQKV, ldsK_dst + i * 512);
        }
        { // stage V^T tile [128 d][64 seq]
            const u16* gv = gv_base + kt * 64;
#pragma unroll
            for (int i = 0; i < 4; ++i)
                GLOAD_LDS16(gv + (size_t)i * 8 * SEQ, ldsV_dst + i * 512);
        }
        __syncthreads();   // drains vmcnt

        // S = Q K^T
        f32x4 S[2][4] = {};
#pragma unroll
        for (int ks = 0; ks < 4; ++ks) {
            bf8 kf[4];
#pragma unroll
            for (int nt = 0; nt < 4; ++nt)
                kf[nt] = *(const bf8*)(Kb + (ks >> 1) * 8192 + (nt * 16 + l15) * 128
                                       + (cswz ^ ((ks & 1) << 6)));
#pragma unroll
            for (int mt = 0; mt < 2; ++mt)
#pragma unroll
                for (int nt = 0; nt < 4; ++nt)
                    S[mt][nt] = __builtin_amdgcn_mfma_f32_16x16x32_bf16(qf[ks][mt], kf[nt], S[mt][nt], 0, 0, 0);
        }

        const bool domask = (kt >= 2 * qt);
#pragma unroll
        for (int mt = 0; mt < 2; ++mt)
#pragma unroll
            for (int r = 0; r < 4; ++r) {
                const int row = qt * 128 + w * 32 + mt * 16 + q4 * 4 + r;
#pragma unroll
                for (int nt = 0; nt < 4; ++nt) {
                    float t = S[mt][nt][r] * cs;
                    if (domask && (kt * 64 + nt * 16 + l15 > row)) t = -1e30f;
                    float p = exp2f(t);
                    plrow[mt][r] += p;
                    ldsP[(w * 32 + mt * 16 + q4 * 4 + r) * PSTR + nt * 16 + l15] = f2bf(p);
                }
            }

        // O += P V   (P rows are wave-private: no barrier needed)
#pragma unroll
        for (int pk = 0; pk < 2; ++pk) {
            bf8 pf[2], vf[8];
#pragma unroll
            for (int mt = 0; mt < 2; ++mt)
                pf[mt] = *(const bf8*)&ldsP[(w * 32 + mt * 16 + l15) * PSTR + pk * 32 + q4 * 8];
#pragma unroll
            for (int nt = 0; nt < 8; ++nt)
                vf[nt] = *(const bf8*)(Vb + (nt * 16 + l15) * 128 + (cswz ^ (pk << 6)));
#pragma unroll
            for (int mt = 0; mt < 2; ++mt)
#pragma unroll
                for (int nt = 0; nt < 8; ++nt)
                    O[mt][nt] = __builtin_amdgcn_mfma_f32_16x16x32_bf16(pf[mt], vf[nt], O[mt][nt], 0, 0, 0);
        }
        __syncthreads();   // all waves done reading K/V/P before next stage
    }

#pragma unroll
    for (int mt = 0; mt < 2; ++mt)
#pragma unroll
        for (int r = 0; r < 4; ++r) {
            float ls = plrow[mt][r];   // row-sum lives across the 16 lanes of this q4 group
#pragma unroll
            for (int off = 1; off <= 8; off <<= 1)
                ls += __shfl_xor(ls, off, 64);
            const float linv = 1.0f / ls;
            const int row = qt * 128 + w * 32 + mt * 16 + q4 * 4 + r;
#pragma unroll
            for (int nt = 0; nt < 8; ++nt)
                aw[(size_t)row * 4096 + qh * HD + nt * 16 + l15] = f2bf(O[mt][nt][r] * linv);
        }
}

// ---------------- launch ----------------

extern "C" void kernel_launch(void* const* d_in, const int* in_sizes, int n_in,
                              void* d_out, int out_size, void* d_ws, size_t ws_size,
                              hipStream_t stream) {
    const float* hs = (const float*)d_in[0];
    const float* wqkv = (const float*)d_in[1];
    const float* wo = (const float*)d_in[2];
    float* out = (float*)d_out;

    char* ws = (char*)d_ws;
    const size_t oHbf = 0;
    const size_t oWqkvT = oHbf + (size_t)SEQ * HIDDEN * 2;          // 16.78 MB
    const size_t oWoT = oWqkvT + (size_t)DQKV * HIDDEN * 2;         // +50.33 MB
    const size_t oXQKV = oWoT + (size_t)HIDDEN * HIDDEN * 2;        // +33.55 MB
    const size_t oVT = oXQKV + (size_t)SEQ * DQKV * 2;              // +25.17 MB
    const size_t oAW = oVT + (size_t)8 * HD * SEQ * 2;              // +4.19 MB
    const size_t total = oAW + (size_t)SEQ * HIDDEN * 2;            // +16.78 MB = 146.8 MB
    if (ws_size < total) return;

    u16* Hbf = (u16*)(ws + oHbf);
    u16* WqkvT = (u16*)(ws + oWqkvT);
    u16* WoT = (u16*)(ws + oWoT);
    u16* XQKV = (u16*)(ws + oXQKV);
    u16* VT = (u16*)(ws + oVT);
    u16* AW = (u16*)(ws + oAW);

    convert_bf16_kernel<<<(SEQ * HIDDEN) / 1024, 256, 0, stream>>>(hs, Hbf);
    transpose_w_kernel<<<(HIDDEN / 64) * (DQKV / 64), 256, 0, stream>>>(wqkv, WqkvT, HIDDEN, DQKV);
    transpose_w_kernel<<<(HIDDEN / 64) * (HIDDEN / 64), 256, 0, stream>>>(wo, WoT, HIDDEN, HIDDEN);
    gemm256_kernel<0><<<8 * 24, 512, 0, stream>>>(Hbf, WqkvT, XQKV, nullptr);   // 192 blocks
    rope_kernel<<<SEQ * 10, 256, 0, stream>>>(XQKV);
    transpose_v_kernel<<<8 * 64, 256, 0, stream>>>(XQKV, VT);
    attn_kernel<<<512, 256, 0, stream>>>(XQKV, VT, AW);
    gemm256_kernel<1><<<8 * 16, 512, 0, stream>>>(AW, WoT, nullptr, out);       // 128 blocks
}

// Round 10
// 508.852 us; speedup vs baseline: 1.1291x; 1.1291x over previous
//
#include <hip/hip_runtime.h>
#include <stdint.h>

typedef unsigned short u16;
typedef __bf16 bf8 __attribute__((ext_vector_type(8)));
typedef float f32x4 __attribute__((ext_vector_type(4)));

#define SEQ 2048
#define HIDDEN 4096
#define DQKV 6144   // 48 heads * 128
#define HD 128

// async global->LDS, 16B/lane. LDS dest is wave-uniform base + lane*16 (m104/m108);
// all staging layouts below are laid out so lane l's element lands at base + l*16B.
#define GLOAD_LDS16(g, l)                                                            \
    __builtin_amdgcn_global_load_lds((const __attribute__((address_space(1))) void*)(g), \
                                     (__attribute__((address_space(3))) void*)(l), 16, 0, 0)

__device__ __forceinline__ u16 f2bf(float f) {
    union { float f; unsigned u; } v{f};
    unsigned r = (v.u + 0x7fff + ((v.u >> 16) & 1)) >> 16;
    return (u16)r;
}
__device__ __forceinline__ float bf2f(u16 b) {
    union { unsigned u; float f; } v;
    v.u = ((unsigned)b) << 16;
    return v.f;
}

// ---------------- fused pre-pass: convert + both weight transposes ----------
// blocks [0,8192): hs fp32 -> Hbf bf16 (1024 elems/block)
// blocks [8192,14336): wqkv [4096][6144] -> WqkvT [6144][4096] bf16
// blocks [14336,18432): wo [4096][4096] -> WoT [4096][4096] bf16
// All three are independent memory-bound ops; one launch removes 2 graph-node
// boundaries and keeps HBM saturated across the phase tails.
__global__ void prep_kernel(const float* __restrict__ hs,
                            const float* __restrict__ wqkv,
                            const float* __restrict__ wo,
                            u16* __restrict__ Hbf,
                            u16* __restrict__ WqkvT,
                            u16* __restrict__ WoT) {
    __shared__ u16 tile[64][65];
    int b = blockIdx.x;
    const int tid = threadIdx.x;
    if (b < 8192) {
        int i = (b * 256 + tid) * 4;
        float4 v = *(const float4*)(hs + i);
        u16 o[4] = {f2bf(v.x), f2bf(v.y), f2bf(v.z), f2bf(v.w)};
        *(uint2*)(Hbf + i) = *(uint2*)o;
        return;
    }
    const float* in;
    u16* out;
    int K, N;
    if (b < 14336) { b -= 8192;  in = wqkv; out = WqkvT; K = HIDDEN; N = DQKV; }
    else           { b -= 14336; in = wo;   out = WoT;   K = HIDDEN; N = HIDDEN; }
    const int tn = N >> 6;
    const int bk = b / tn, bn = b % tn;
    const int k0 = bk * 64, n0 = bn * 64;
    const int c = tid & 63, r0 = tid >> 6;
#pragma unroll
    for (int r = r0; r < 64; r += 4)
        tile[r][c] = f2bf(in[(size_t)(k0 + r) * N + n0 + c]);
    __syncthreads();
#pragma unroll
    for (int r = r0; r < 64; r += 4)
        out[(size_t)(n0 + r) * K + k0 + c] = tile[c][r];
}

// ---------------- fused RoPE + V-transpose ----------------
// blocks [0,20480): RoPE in-place on Q/K heads (cols 0..5119 of xqkv)
// blocks [20480,20992): V heads (cols 5120..6143) -> VT [8][128][2048]
// Disjoint column ranges of xqkv -> safe to run concurrently in one launch.
__global__ void rope_tv_kernel(u16* __restrict__ x, u16* __restrict__ vt) {
    __shared__ u16 tile[64][65];
    int b = blockIdx.x;
    const int tid = threadIdx.x;
    if (b < 20480) {
        const int row = b / 10, hg = b % 10;
        const int head = hg * 4 + (tid >> 6), j = tid & 63;
        u16* p = x + (size_t)row * DQKV + head * HD + j;
        float x1 = bf2f(p[0]), x2 = bf2f(p[64]);
        float inv = exp2f(-(float)j * 0.20762050593045952f); // log2(10000)/64
        float s, c;
        sincosf((float)row * inv, &s, &c);
        p[0] = f2bf(x1 * c - x2 * s);
        p[64] = f2bf(x1 * s + x2 * c);
        return;
    }
    b -= 20480;
    const int h = b >> 6;
    const int t = b & 63;
    const int s0 = (t >> 1) * 64, d0 = (t & 1) * 64;
    const int c = tid & 63, r0 = tid >> 6;
    const u16* src = x + (40 + h) * HD + d0;
#pragma unroll
    for (int r = r0; r < 64; r += 4)
        tile[r][c] = src[(size_t)(s0 + r) * DQKV + c];
    __syncthreads();
    u16* dst = vt + ((size_t)h * HD + d0) * SEQ + s0;
#pragma unroll
    for (int r = r0; r < 64; r += 4)
        dst[(size_t)r * SEQ + c] = tile[c][r];
}

// ---------------- GEMM: C[M][*] = A[M][4096] * BT[N][4096]^T ----------------
// R5 config, best measured: 107.5 us, 0 bank conflicts, 958 TF. Reverted here
// after the 256x256 m201-geometry experiment (R9: +14% per-block rate but 75%
// fill -> net loss). Six structural variants (0.375-0.458 reads/MFMA, 1-3
// blk/CU, lockstep vs pipelined) all land 930-1090 TF-equiv: family ceiling.
// MODE 0: 256x192 tile (8x32 grid), bf16 out stride 6144, waves 2Mx4N.
// MODE 1: 128x256 tile (16x16 grid), f32 out stride 4096, waves 2Mx4N.
// T1 XCD chunking (FETCH -10%). Swizzle (T2): logical (r,c16B) at phys
// c ^ (r&7) via pre-permuted gload source col (rule #21); zero conflicts
// measured. Counted vmcnt(NL) never 0 in steady state (T4). setprio (T5).
template <int BM, int BN, int MODE>
__global__ __launch_bounds__(512, 2) void gemm8p_kernel(const u16* __restrict__ A,
                                                        const u16* __restrict__ BT,
                                                        u16* __restrict__ Cbf,
                                                        float* __restrict__ Cf) {
    constexpr int WM = BM / 32;          // m-frags per wave
    constexpr int WN = BN / 64;          // n-frags per wave
    constexpr int MP = WM / 4;           // m-frags per phase
    constexpr int NLA = BM / 64, NLB = BN / 64, NL = NLA + NLB;
    constexpr int NBN = ((MODE == 0) ? DQKV : HIDDEN) / BN;
    constexpr int NBM = SEQ / BM;
    constexpr int CSTR = (MODE == 0) ? DQKV : HIDDEN;
    constexpr int NT = 64;               // K / 64
    static_assert(NBM * NBN == 256, "grid must be exactly 256 blocks");
    __shared__ __align__(16) u16 lds[2][(BM + BN) * 64];

    const int tid = threadIdx.x;
    const int w = tid >> 6, l = tid & 63, l15 = l & 15, q4 = l >> 4;
    const int wm = w >> 2, wn = w & 3;

    // T1: XCD-aware 2D chunking (xcd = blockIdx%8 round-robin assumption).
    const int xcd = blockIdx.x & 7, wi = blockIdx.x >> 3;
    int bm, bn;
    if constexpr (NBN == 32) {           // 8 x 32 grid (MODE 0)
        bm = (xcd >> 2) * 4 + (wi >> 3);
        bn = (xcd & 3) * 8 + (wi & 7);
    } else {                             // 16 x 16 grid (MODE 1)
        bm = (xcd & 3) * 4 + (wi >> 3);
        bn = (xcd >> 2) * 8 + (wi & 7);
    }

    // staging: thread tid fills phys bytes [line*8192 + tid*16, +16) of a region
    // = logical row line*64 + tid/8, col ((tid&7)^((tid>>3)&7))*16 (swizzled src)
    const int srow = tid >> 3;
    const int scol = ((tid & 7) ^ ((tid >> 3) & 7)) << 4;
    const char* spA[NLA];
    const char* spB[NLB];
#pragma unroll
    for (int L = 0; L < NLA; ++L)
        spA[L] = (const char*)(A + (size_t)(bm * BM + L * 64 + srow) * 4096) + scol;
#pragma unroll
    for (int L = 0; L < NLB; ++L)
        spB[L] = (const char*)(BT + (size_t)(bn * BN + L * 64 + srow) * 4096) + scol;

#define STG_A(L, tt, b) GLOAD_LDS16(spA[L] + (size_t)(tt) * 128, &lds[b][(L) * 4096 + w * 512])
#define STG_B(L, tt, b) GLOAD_LDS16(spB[L] + (size_t)(tt) * 128, &lds[b][BM * 64 + (L) * 4096 + w * 512])

    // prologue: stage tiles 0 and 1, wait for tile 0 only (NL of tile 1 in flight)
#pragma unroll
    for (int L = 0; L < NLA; ++L) STG_A(L, 0, 0);
#pragma unroll
    for (int L = 0; L < NLB; ++L) STG_B(L, 0, 0);
#pragma unroll
    for (int L = 0; L < NLA; ++L) STG_A(L, 1, 1);
#pragma unroll
    for (int L = 0; L < NLB; ++L) STG_B(L, 1, 1);
    if constexpr (NL == 7) asm volatile("s_waitcnt vmcnt(7)" ::: "memory");
    else                   asm volatile("s_waitcnt vmcnt(6)" ::: "memory");
    asm volatile("s_barrier" ::: "memory");

    // read-side swizzle: frag row = 16*frag + l15 -> row&7 == l15&7
    const int c0x = (q4 * 16) ^ ((l15 & 7) << 4);
    const int c1x = c0x ^ 64;

    f32x4 acc[WM][WN] = {};
    bf8 breg[WN][2];

#pragma unroll 1
    for (int t = 0; t < NT; ++t) {
        const int cur = t & 1;
        const char* ldsA = (const char*)&lds[cur][0];
        const char* ldsB = ldsA + BM * 128;
#pragma unroll
        for (int p = 0; p < 4; ++p) {
            // stage tile t+2 into the regions of buf[cur] that died last phase
            if (p == 1 && t < NT - 2) {
#pragma unroll
                for (int L = 0; L < NLB; ++L) STG_B(L, t + 2, cur);
            }
            if constexpr (BM == 256) {
                // A lines 0,2 (rows 0-63 of each wm-half) are read only in p0/p1
                if (p == 2 && t < NT - 2) {
                    STG_A(0, t + 2, cur);
                    STG_A(2, t + 2, cur);
                }
            }
            bf8 areg[MP][2];
#pragma unroll
            for (int j = 0; j < MP; ++j) {
                const char* rp = ldsA + (wm * (BM / 2) + (p * MP + j) * 16 + l15) * 128;
                areg[j][0] = *(const bf8*)(rp + c0x);
                areg[j][1] = *(const bf8*)(rp + c1x);
            }
            if (p == 0) {
#pragma unroll
                for (int nf = 0; nf < WN; ++nf) {
                    const char* rp = ldsB + (wn * (WN * 16) + nf * 16 + l15) * 128;
                    breg[nf][0] = *(const bf8*)(rp + c0x);
                    breg[nf][1] = *(const bf8*)(rp + c1x);
                }
            }
            asm volatile("s_barrier" ::: "memory");
            asm volatile("s_waitcnt lgkmcnt(0)" ::: "memory");
            __builtin_amdgcn_s_setprio(1);
#pragma unroll
            for (int j = 0; j < MP; ++j)
#pragma unroll
                for (int nf = 0; nf < WN; ++nf)
#pragma unroll
                    for (int ks = 0; ks < 2; ++ks)
                        acc[p * MP + j][nf] = __builtin_amdgcn_mfma_f32_16x16x32_bf16(
                            areg[j][ks], breg[nf][ks], acc[p * MP + j][nf], 0, 0, 0);
            __builtin_amdgcn_s_setprio(0);
            asm volatile("s_barrier" ::: "memory");
        }
        // boundary: stage the A lines that stayed live through p3, then counted
        // vmcnt -- guarantees tile t+1 (issued during t-1) fully landed, while
        // tile t+2's NL loads stay in flight across the barrier.
        if (t < NT - 2) {
            if constexpr (BM == 256) { STG_A(1, t + 2, cur); STG_A(3, t + 2, cur); }
            else                     { STG_A(0, t + 2, cur); STG_A(1, t + 2, cur); }
            if constexpr (NL == 7) asm volatile("s_waitcnt vmcnt(7)" ::: "memory");
            else                   asm volatile("s_waitcnt vmcnt(6)" ::: "memory");
        } else if (t == NT - 2) {
            asm volatile("s_waitcnt vmcnt(0)" ::: "memory");
        }
        asm volatile("s_barrier" ::: "memory");
    }
#undef STG_A
#undef STG_B

    const int rowb = bm * BM + wm * (BM / 2);
    const int colb = bn * BN + wn * (WN * 16);
#pragma unroll
    for (int mf = 0; mf < WM; ++mf)
#pragma unroll
        for (int nf = 0; nf < WN; ++nf)
#pragma unroll
            for (int r = 0; r < 4; ++r) {
                const int row = rowb + mf * 16 + q4 * 4 + r;
                const int col = colb + nf * 16 + l15;
                if constexpr (MODE == 0)
                    Cbf[(size_t)row * CSTR + col] = f2bf(acc[mf][nf][r]);
                else
                    Cf[(size_t)row * CSTR + col] = acc[mf][nf][r];
            }
}

// ---------------- flash attention ----------------
// grid: 512 = 16 q-tiles * 32 heads. block 256 = 4 waves, each wave owns 32 Q rows.
// No running max (scores bounded), unnormalized p=exp2(s*cs), per-lane row-sum,
// one shuffle-reduce + normalize at the end. K/V in GEMM-shaped zero-conflict
// swizzled LDS sub-tiles (R7).
#define PSTR 72   // P row stride in shorts: 64 cols + 8 pad (2-way alias = free)
__global__ __launch_bounds__(256) void attn_kernel(const u16* __restrict__ xqkv,
                                                   const u16* __restrict__ vt,
                                                   u16* __restrict__ aw) {
    __shared__ __align__(16) u16 sm[16384 + 128 * PSTR];
    const int tid = threadIdx.x, w = tid >> 6, l = tid & 63, l15 = l & 15, q4 = l >> 4;
    const int qh = blockIdx.x & 31;
    const int qslot = blockIdx.x >> 5;
    // complementary pairing: blocks b and b+256 get qt summing to 15 (tail balance)
    const int qt = (qslot < 8) ? qslot : 23 - qslot;
    const int kh = qh >> 2;

    { // stage Q tile: [ks=w][row 128][32], async (one-time; layout legacy)
        const u16* gq = xqkv + (size_t)(qt * 128 + (l >> 2)) * DQKV + qh * HD + w * 32 + (l & 3) * 8;
#pragma unroll
        for (int i = 0; i < 8; ++i)
            GLOAD_LDS16(gq + (size_t)i * 16 * DQKV, &sm[w * 4096 + i * 512]);
    }
    __syncthreads();
    bf8 qf[4][2];
#pragma unroll
    for (int ks = 0; ks < 4; ++ks)
#pragma unroll
        for (int mt = 0; mt < 2; ++mt)
            qf[ks][mt] = *(const bf8*)&sm[ks * 4096 + (w * 32 + mt * 16 + l15) * 32 + q4 * 8];
    __syncthreads();

    f32x4 O[2][8] = {};
    float plrow[2][4] = {};   // per-lane unnormalized row-sum partials

    u16* ldsK = sm;           // [2][64][64] shorts
    u16* ldsV = sm + 8192;    // [128][64] shorts
    u16* ldsP = sm + 16384;
    const int nkt = 2 * qt + 2;
    const float cs = 0.12751744f; // (1/sqrt(128)) * log2(e)

    // staging source swizzle (GEMM-verified): lane l covers phys row-in-group
    // l>>3, slot l&7 -> loads logical col ((l&7)^(l>>3))*8 elems
    const int sr8 = l >> 3;
    const int sc8 = (l & 7) ^ sr8;
    // K: wave w stages d-half (w&1), seq rows (w>>1)*32..+32
    const u16* gk_base = xqkv + (size_t)((w >> 1) * 32 + sr8) * DQKV + (32 + kh) * HD + (w & 1) * 64 + sc8 * 8;
    u16* ldsK_dst = ldsK + (w & 1) * 4096 + (w >> 1) * 2048;
    // V: wave w stages d-rows w*32..+32 (cols = seq kt*64..+64)
    const u16* gv_base = vt + ((size_t)kh * HD + w * 32 + sr8) * SEQ + sc8 * 8;
    u16* ldsV_dst = ldsV + w * 2048;

    const int cswz = (q4 ^ (l15 & 7)) << 4;   // read-side swizzled byte col
    const char* Kb = (const char*)ldsK;
    const char* Vb = (const char*)ldsV;

    for (int kt = 0; kt < nkt; ++kt) {
        { // stage K tile [64 seq][128 d] as 2 GEMM-shaped sub-tiles
            const u16* gk = gk_base + (size_t)(kt * 64) * DQKV;
#pragma unroll
            for (int i = 0; i < 4; ++i)
                GLOAD_LDS16(gk + (size_t)i * 8 * DQKV, ldsK_dst + i * 512);
        }
        { // stage V^T tile [128 d][64 seq]
            const u16* gv = gv_base + kt * 64;
#pragma unroll
            for (int i = 0; i < 4; ++i)
                GLOAD_LDS16(gv + (size_t)i * 8 * SEQ, ldsV_dst + i * 512);
        }
        __syncthreads();   // drains vmcnt

        // S = Q K^T
        f32x4 S[2][4] = {};
#pragma unroll
        for (int ks = 0; ks < 4; ++ks) {
            bf8 kf[4];
#pragma unroll
            for (int nt = 0; nt < 4; ++nt)
                kf[nt] = *(const bf8*)(Kb + (ks >> 1) * 8192 + (nt * 16 + l15) * 128
                                       + (cswz ^ ((ks & 1) << 6)));
#pragma unroll
            for (int mt = 0; mt < 2; ++mt)
#pragma unroll
                for (int nt = 0; nt < 4; ++nt)
                    S[mt][nt] = __builtin_amdgcn_mfma_f32_16x16x32_bf16(qf[ks][mt], kf[nt], S[mt][nt], 0, 0, 0);
        }

        const bool domask = (kt >= 2 * qt);
#pragma unroll
        for (int mt = 0; mt < 2; ++mt)
#pragma unroll
            for (int r = 0; r < 4; ++r) {
                const int row = qt * 128 + w * 32 + mt * 16 + q4 * 4 + r;
#pragma unroll
                for (int nt = 0; nt < 4; ++nt) {
                    float t = S[mt][nt][r] * cs;
                    if (domask && (kt * 64 + nt * 16 + l15 > row)) t = -1e30f;
                    float p = exp2f(t);
                    plrow[mt][r] += p;
                    ldsP[(w * 32 + mt * 16 + q4 * 4 + r) * PSTR + nt * 16 + l15] = f2bf(p);
                }
            }

        // O += P V   (P rows are wave-private: no barrier needed)
#pragma unroll
        for (int pk = 0; pk < 2; ++pk) {
            bf8 pf[2], vf[8];
#pragma unroll
            for (int mt = 0; mt < 2; ++mt)
                pf[mt] = *(const bf8*)&ldsP[(w * 32 + mt * 16 + l15) * PSTR + pk * 32 + q4 * 8];
#pragma unroll
            for (int nt = 0; nt < 8; ++nt)
                vf[nt] = *(const bf8*)(Vb + (nt * 16 + l15) * 128 + (cswz ^ (pk << 6)));
#pragma unroll
            for (int mt = 0; mt < 2; ++mt)
#pragma unroll
                for (int nt = 0; nt < 8; ++nt)
                    O[mt][nt] = __builtin_amdgcn_mfma_f32_16x16x32_bf16(pf[mt], vf[nt], O[mt][nt], 0, 0, 0);
        }
        __syncthreads();   // all waves done reading K/V/P before next stage
    }

#pragma unroll
    for (int mt = 0; mt < 2; ++mt)
#pragma unroll
        for (int r = 0; r < 4; ++r) {
            float ls = plrow[mt][r];   // row-sum lives across the 16 lanes of this q4 group
#pragma unroll
            for (int off = 1; off <= 8; off <<= 1)
                ls += __shfl_xor(ls, off, 64);
            const float linv = 1.0f / ls;
            const int row = qt * 128 + w * 32 + mt * 16 + q4 * 4 + r;
#pragma unroll
            for (int nt = 0; nt < 8; ++nt)
                aw[(size_t)row * 4096 + qh * HD + nt * 16 + l15] = f2bf(O[mt][nt][r] * linv);
        }
}

// ---------------- launch ----------------

extern "C" void kernel_launch(void* const* d_in, const int* in_sizes, int n_in,
                              void* d_out, int out_size, void* d_ws, size_t ws_size,
                              hipStream_t stream) {
    const float* hs = (const float*)d_in[0];
    const float* wqkv = (const float*)d_in[1];
    const float* wo = (const float*)d_in[2];
    float* out = (float*)d_out;

    char* ws = (char*)d_ws;
    const size_t oHbf = 0;
    const size_t oWqkvT = oHbf + (size_t)SEQ * HIDDEN * 2;          // 16.78 MB
    const size_t oWoT = oWqkvT + (size_t)DQKV * HIDDEN * 2;         // +50.33 MB
    const size_t oXQKV = oWoT + (size_t)HIDDEN * HIDDEN * 2;        // +33.55 MB
    const size_t oVT = oXQKV + (size_t)SEQ * DQKV * 2;              // +25.17 MB
    const size_t oAW = oVT + (size_t)8 * HD * SEQ * 2;              // +4.19 MB
    const size_t total = oAW + (size_t)SEQ * HIDDEN * 2;            // +16.78 MB = 146.8 MB
    if (ws_size < total) return;

    u16* Hbf = (u16*)(ws + oHbf);
    u16* WqkvT = (u16*)(ws + oWqkvT);
    u16* WoT = (u16*)(ws + oWoT);
    u16* XQKV = (u16*)(ws + oXQKV);
    u16* VT = (u16*)(ws + oVT);
    u16* AW = (u16*)(ws + oAW);

    // 5 kernels (was 8): fused prep, GEMM0, fused rope+tv, attn, GEMM1
    prep_kernel<<<18432, 256, 0, stream>>>(hs, wqkv, wo, Hbf, WqkvT, WoT);
    gemm8p_kernel<256, 192, 0><<<256, 512, 0, stream>>>(Hbf, WqkvT, XQKV, nullptr);  // 8x32 grid
    rope_tv_kernel<<<20992, 256, 0, stream>>>(XQKV, VT);
    attn_kernel<<<512, 256, 0, stream>>>(XQKV, VT, AW);
    gemm8p_kernel<128, 256, 1><<<256, 512, 0, stream>>>(AW, WoT, nullptr, out);      // 16x16 grid
}

// Round 11
// 494.623 us; speedup vs baseline: 1.1616x; 1.0288x over previous
//
#include <hip/hip_runtime.h>
#include <stdint.h>

typedef unsigned short u16;
typedef __bf16 bf8 __attribute__((ext_vector_type(8)));
typedef float f32x4 __attribute__((ext_vector_type(4)));

#define SEQ 2048
#define HIDDEN 4096
#define DQKV 6144   // 48 heads * 128
#define HD 128

// async global->LDS, 16B/lane. LDS dest is wave-uniform base + lane*16 (m104/m108);
// all staging layouts below are laid out so lane l's element lands at base + l*16B.
#define GLOAD_LDS16(g, l)                                                            \
    __builtin_amdgcn_global_load_lds((const __attribute__((address_space(1))) void*)(g), \
                                     (__attribute__((address_space(3))) void*)(l), 16, 0, 0)

__device__ __forceinline__ u16 f2bf(float f) {
    union { float f; unsigned u; } v{f};
    unsigned r = (v.u + 0x7fff + ((v.u >> 16) & 1)) >> 16;
    return (u16)r;
}
__device__ __forceinline__ float bf2f(u16 b) {
    union { unsigned u; float f; } v;
    v.u = ((unsigned)b) << 16;
    return v.f;
}

// ---------------- fused pre-pass: convert + both weight transposes ----------
// blocks [0,8192): hs fp32 -> Hbf bf16 (1024 elems/block)
// blocks [8192,14336): wqkv [4096][6144] -> WqkvT [6144][4096] bf16
// blocks [14336,18432): wo [4096][4096] -> WoT [4096][4096] bf16
__global__ void prep_kernel(const float* __restrict__ hs,
                            const float* __restrict__ wqkv,
                            const float* __restrict__ wo,
                            u16* __restrict__ Hbf,
                            u16* __restrict__ WqkvT,
                            u16* __restrict__ WoT) {
    __shared__ u16 tile[64][65];
    int b = blockIdx.x;
    const int tid = threadIdx.x;
    if (b < 8192) {
        int i = (b * 256 + tid) * 4;
        float4 v = *(const float4*)(hs + i);
        u16 o[4] = {f2bf(v.x), f2bf(v.y), f2bf(v.z), f2bf(v.w)};
        *(uint2*)(Hbf + i) = *(uint2*)o;
        return;
    }
    const float* in;
    u16* out;
    int K, N;
    if (b < 14336) { b -= 8192;  in = wqkv; out = WqkvT; K = HIDDEN; N = DQKV; }
    else           { b -= 14336; in = wo;   out = WoT;   K = HIDDEN; N = HIDDEN; }
    const int tn = N >> 6;
    const int bk = b / tn, bn = b % tn;
    const int k0 = bk * 64, n0 = bn * 64;
    const int c = tid & 63, r0 = tid >> 6;
#pragma unroll
    for (int r = r0; r < 64; r += 4)
        tile[r][c] = f2bf(in[(size_t)(k0 + r) * N + n0 + c]);
    __syncthreads();
#pragma unroll
    for (int r = r0; r < 64; r += 4)
        out[(size_t)(n0 + r) * K + k0 + c] = tile[c][r];
}

// ---------------- fused RoPE + V-transpose ----------------
// blocks [0,20480): RoPE in-place on Q/K heads (cols 0..5119 of xqkv)
// blocks [20480,20992): V heads (cols 5120..6143) -> VT [8][128][2048]
__global__ void rope_tv_kernel(u16* __restrict__ x, u16* __restrict__ vt) {
    __shared__ u16 tile[64][65];
    int b = blockIdx.x;
    const int tid = threadIdx.x;
    if (b < 20480) {
        const int row = b / 10, hg = b % 10;
        const int head = hg * 4 + (tid >> 6), j = tid & 63;
        u16* p = x + (size_t)row * DQKV + head * HD + j;
        float x1 = bf2f(p[0]), x2 = bf2f(p[64]);
        float inv = exp2f(-(float)j * 0.20762050593045952f); // log2(10000)/64
        float s, c;
        sincosf((float)row * inv, &s, &c);
        p[0] = f2bf(x1 * c - x2 * s);
        p[64] = f2bf(x1 * s + x2 * c);
        return;
    }
    b -= 20480;
    const int h = b >> 6;
    const int t = b & 63;
    const int s0 = (t >> 1) * 64, d0 = (t & 1) * 64;
    const int c = tid & 63, r0 = tid >> 6;
    const u16* src = x + (40 + h) * HD + d0;
#pragma unroll
    for (int r = r0; r < 64; r += 4)
        tile[r][c] = src[(size_t)(s0 + r) * DQKV + c];
    __syncthreads();
    u16* dst = vt + ((size_t)h * HD + d0) * SEQ + s0;
#pragma unroll
    for (int r = r0; r < 64; r += 4)
        dst[(size_t)r * SEQ + c] = tile[c][r];
}

// ---------------- GEMM: C[M][*] = A[M][4096] * BT[N][4096]^T ----------------
// R5 config, best measured: 107.5 us, 0 bank conflicts, 958 TF (family ceiling
// across six structural variants). Unchanged from round 10.
template <int BM, int BN, int MODE>
__global__ __launch_bounds__(512, 2) void gemm8p_kernel(const u16* __restrict__ A,
                                                        const u16* __restrict__ BT,
                                                        u16* __restrict__ Cbf,
                                                        float* __restrict__ Cf) {
    constexpr int WM = BM / 32;          // m-frags per wave
    constexpr int WN = BN / 64;          // n-frags per wave
    constexpr int MP = WM / 4;           // m-frags per phase
    constexpr int NLA = BM / 64, NLB = BN / 64, NL = NLA + NLB;
    constexpr int NBN = ((MODE == 0) ? DQKV : HIDDEN) / BN;
    constexpr int NBM = SEQ / BM;
    constexpr int CSTR = (MODE == 0) ? DQKV : HIDDEN;
    constexpr int NT = 64;               // K / 64
    static_assert(NBM * NBN == 256, "grid must be exactly 256 blocks");
    __shared__ __align__(16) u16 lds[2][(BM + BN) * 64];

    const int tid = threadIdx.x;
    const int w = tid >> 6, l = tid & 63, l15 = l & 15, q4 = l >> 4;
    const int wm = w >> 2, wn = w & 3;

    // T1: XCD-aware 2D chunking (xcd = blockIdx%8 round-robin assumption).
    const int xcd = blockIdx.x & 7, wi = blockIdx.x >> 3;
    int bm, bn;
    if constexpr (NBN == 32) {           // 8 x 32 grid (MODE 0)
        bm = (xcd >> 2) * 4 + (wi >> 3);
        bn = (xcd & 3) * 8 + (wi & 7);
    } else {                             // 16 x 16 grid (MODE 1)
        bm = (xcd & 3) * 4 + (wi >> 3);
        bn = (xcd >> 2) * 8 + (wi & 7);
    }

    // staging: thread tid fills phys bytes [line*8192 + tid*16, +16) of a region
    // = logical row line*64 + tid/8, col ((tid&7)^((tid>>3)&7))*16 (swizzled src)
    const int srow = tid >> 3;
    const int scol = ((tid & 7) ^ ((tid >> 3) & 7)) << 4;
    const char* spA[NLA];
    const char* spB[NLB];
#pragma unroll
    for (int L = 0; L < NLA; ++L)
        spA[L] = (const char*)(A + (size_t)(bm * BM + L * 64 + srow) * 4096) + scol;
#pragma unroll
    for (int L = 0; L < NLB; ++L)
        spB[L] = (const char*)(BT + (size_t)(bn * BN + L * 64 + srow) * 4096) + scol;

#define STG_A(L, tt, b) GLOAD_LDS16(spA[L] + (size_t)(tt) * 128, &lds[b][(L) * 4096 + w * 512])
#define STG_B(L, tt, b) GLOAD_LDS16(spB[L] + (size_t)(tt) * 128, &lds[b][BM * 64 + (L) * 4096 + w * 512])

    // prologue: stage tiles 0 and 1, wait for tile 0 only (NL of tile 1 in flight)
#pragma unroll
    for (int L = 0; L < NLA; ++L) STG_A(L, 0, 0);
#pragma unroll
    for (int L = 0; L < NLB; ++L) STG_B(L, 0, 0);
#pragma unroll
    for (int L = 0; L < NLA; ++L) STG_A(L, 1, 1);
#pragma unroll
    for (int L = 0; L < NLB; ++L) STG_B(L, 1, 1);
    if constexpr (NL == 7) asm volatile("s_waitcnt vmcnt(7)" ::: "memory");
    else                   asm volatile("s_waitcnt vmcnt(6)" ::: "memory");
    asm volatile("s_barrier" ::: "memory");

    // read-side swizzle: frag row = 16*frag + l15 -> row&7 == l15&7
    const int c0x = (q4 * 16) ^ ((l15 & 7) << 4);
    const int c1x = c0x ^ 64;

    f32x4 acc[WM][WN] = {};
    bf8 breg[WN][2];

#pragma unroll 1
    for (int t = 0; t < NT; ++t) {
        const int cur = t & 1;
        const char* ldsA = (const char*)&lds[cur][0];
        const char* ldsB = ldsA + BM * 128;
#pragma unroll
        for (int p = 0; p < 4; ++p) {
            // stage tile t+2 into the regions of buf[cur] that died last phase
            if (p == 1 && t < NT - 2) {
#pragma unroll
                for (int L = 0; L < NLB; ++L) STG_B(L, t + 2, cur);
            }
            if constexpr (BM == 256) {
                // A lines 0,2 (rows 0-63 of each wm-half) are read only in p0/p1
                if (p == 2 && t < NT - 2) {
                    STG_A(0, t + 2, cur);
                    STG_A(2, t + 2, cur);
                }
            }
            bf8 areg[MP][2];
#pragma unroll
            for (int j = 0; j < MP; ++j) {
                const char* rp = ldsA + (wm * (BM / 2) + (p * MP + j) * 16 + l15) * 128;
                areg[j][0] = *(const bf8*)(rp + c0x);
                areg[j][1] = *(const bf8*)(rp + c1x);
            }
            if (p == 0) {
#pragma unroll
                for (int nf = 0; nf < WN; ++nf) {
                    const char* rp = ldsB + (wn * (WN * 16) + nf * 16 + l15) * 128;
                    breg[nf][0] = *(const bf8*)(rp + c0x);
                    breg[nf][1] = *(const bf8*)(rp + c1x);
                }
            }
            asm volatile("s_barrier" ::: "memory");
            asm volatile("s_waitcnt lgkmcnt(0)" ::: "memory");
            __builtin_amdgcn_s_setprio(1);
#pragma unroll
            for (int j = 0; j < MP; ++j)
#pragma unroll
                for (int nf = 0; nf < WN; ++nf)
#pragma unroll
                    for (int ks = 0; ks < 2; ++ks)
                        acc[p * MP + j][nf] = __builtin_amdgcn_mfma_f32_16x16x32_bf16(
                            areg[j][ks], breg[nf][ks], acc[p * MP + j][nf], 0, 0, 0);
            __builtin_amdgcn_s_setprio(0);
            asm volatile("s_barrier" ::: "memory");
        }
        // boundary: stage the A lines that stayed live through p3, then counted
        // vmcnt -- guarantees tile t+1 (issued during t-1) fully landed, while
        // tile t+2's NL loads stay in flight across the barrier.
        if (t < NT - 2) {
            if constexpr (BM == 256) { STG_A(1, t + 2, cur); STG_A(3, t + 2, cur); }
            else                     { STG_A(0, t + 2, cur); STG_A(1, t + 2, cur); }
            if constexpr (NL == 7) asm volatile("s_waitcnt vmcnt(7)" ::: "memory");
            else                   asm volatile("s_waitcnt vmcnt(6)" ::: "memory");
        } else if (t == NT - 2) {
            asm volatile("s_waitcnt vmcnt(0)" ::: "memory");
        }
        asm volatile("s_barrier" ::: "memory");
    }
#undef STG_A
#undef STG_B

    const int rowb = bm * BM + wm * (BM / 2);
    const int colb = bn * BN + wn * (WN * 16);
#pragma unroll
    for (int mf = 0; mf < WM; ++mf)
#pragma unroll
        for (int nf = 0; nf < WN; ++nf)
#pragma unroll
            for (int r = 0; r < 4; ++r) {
                const int row = rowb + mf * 16 + q4 * 4 + r;
                const int col = colb + nf * 16 + l15;
                if constexpr (MODE == 0)
                    Cbf[(size_t)row * CSTR + col] = f2bf(acc[mf][nf][r]);
                else
                    Cf[(size_t)row * CSTR + col] = acc[mf][nf][r];
            }
}

// ---------------- flash attention ----------------
// grid: 512 = 16 q-tiles * 32 heads. block 256 = 4 waves, each wave owns 32 Q rows.
// No running max (scores bounded), unnormalized p=exp2(s*cs), per-lane row-sum,
// one shuffle-reduce + normalize at the end.
// NEW this round: K/V DOUBLE-BUFFERED (T14/T3 analog). Old loop exposed the
// full K/V load latency every k-tile (issue -> __syncthreads drains vmcnt(0)
// -> compute, no overlap; MfmaUtil 12.6%, all utils low). Now tile kt+1's 8
// gload_lds issue right after the top-of-tile barrier and land during kt's
// compute; ONE barrier per k-tile (top __syncthreads: own vmcnt drained before
// barrier => all waves' staged data visible; prev-buffer readers precede it
// in program order). LDS 81920 B = exactly 2 blocks/CU.
// P moves to [128][64] with the zero-conflict-verified XOR swizzle
// (byte col ^ ((row&7)<<4) both sides; read pattern == R2 GEMM pattern,
// measured 0 conflicts; writes 2-way aliased = free per m136).
__global__ __launch_bounds__(256) void attn_kernel(const u16* __restrict__ xqkv,
                                                   const u16* __restrict__ vt,
                                                   u16* __restrict__ aw) {
    // shorts: [0,16384) K dbuf [2][2][64][64]; [16384,32768) V dbuf [2][128][64];
    // [32768,40960) P [128][64] swizzled. Q staged once into [0,16384).
    __shared__ __align__(16) u16 sm[40960];
    const int tid = threadIdx.x, w = tid >> 6, l = tid & 63, l15 = l & 15, q4 = l >> 4;
    const int qh = blockIdx.x & 31;
    const int qslot = blockIdx.x >> 5;
    // complementary pairing: blocks b and b+256 get qt summing to 15 (tail balance)
    const int qt = (qslot < 8) ? qslot : 23 - qslot;
    const int kh = qh >> 2;

    { // stage Q tile: [ks=w][row 128][32], async (K-dbuf area, read then dead)
        const u16* gq = xqkv + (size_t)(qt * 128 + (l >> 2)) * DQKV + qh * HD + w * 32 + (l & 3) * 8;
#pragma unroll
        for (int i = 0; i < 8; ++i)
            GLOAD_LDS16(gq + (size_t)i * 16 * DQKV, &sm[w * 4096 + i * 512]);
    }
    __syncthreads();
    bf8 qf[4][2];
#pragma unroll
    for (int ks = 0; ks < 4; ++ks)
#pragma unroll
        for (int mt = 0; mt < 2; ++mt)
            qf[ks][mt] = *(const bf8*)&sm[ks * 4096 + (w * 32 + mt * 16 + l15) * 32 + q4 * 8];
    __syncthreads();   // all waves done with Q before K(0) overwrites

    f32x4 O[2][8] = {};
    float plrow[2][4] = {};   // per-lane unnormalized row-sum partials

    u16* smK = sm;            // [2 buf][2 d-half][64][64]
    u16* smV = sm + 16384;    // [2 buf][128][64]
    char* Pb = (char*)(sm + 32768);
    const int nkt = 2 * qt + 2;
    const float cs = 0.12751744f; // (1/sqrt(128)) * log2(e)

    // staging source swizzle (GEMM-verified): lane l covers phys row-in-group
    // l>>3, slot l&7 -> loads logical col ((l&7)^(l>>3))*8 elems
    const int sr8 = l >> 3;
    const int sc8 = (l & 7) ^ sr8;
    const u16* gk_base = xqkv + (size_t)((w >> 1) * 32 + sr8) * DQKV + (32 + kh) * HD + (w & 1) * 64 + sc8 * 8;
    const int kdst = (w & 1) * 4096 + (w >> 1) * 2048;
    const u16* gv_base = vt + ((size_t)kh * HD + w * 32 + sr8) * SEQ + sc8 * 8;
    const int vdst = w * 2048;

    const int cswz = (q4 ^ (l15 & 7)) << 4;   // K/V read-side swizzled byte col

    // prologue: stage kt=0 into buffer 0
    {
#pragma unroll
        for (int i = 0; i < 4; ++i)
            GLOAD_LDS16(gk_base + (size_t)i * 8 * DQKV, smK + kdst + i * 512);
#pragma unroll
        for (int i = 0; i < 4; ++i)
            GLOAD_LDS16(gv_base + (size_t)i * 8 * SEQ, smV + vdst + i * 512);
    }

    for (int kt = 0; kt < nkt; ++kt) {
        // own vmcnt drained then barrier: kt's staged data visible to all waves;
        // also guarantees all waves finished reading buf[kt^1] (prev compute).
        __syncthreads();
        if (kt + 1 < nkt) {   // issue kt+1 into the other buffer; lands under compute
            const int nxt = (kt + 1) & 1;
            const u16* gk = gk_base + (size_t)((kt + 1) * 64) * DQKV;
#pragma unroll
            for (int i = 0; i < 4; ++i)
                GLOAD_LDS16(gk + (size_t)i * 8 * DQKV, smK + nxt * 8192 + kdst + i * 512);
            const u16* gv = gv_base + (kt + 1) * 64;
#pragma unroll
            for (int i = 0; i < 4; ++i)
                GLOAD_LDS16(gv + (size_t)i * 8 * SEQ, smV + nxt * 8192 + vdst + i * 512);
        }
        const char* Kb = (const char*)(smK + (kt & 1) * 8192);
        const char* Vb = (const char*)(smV + (kt & 1) * 8192);

        // S = Q K^T
        f32x4 S[2][4] = {};
#pragma unroll
        for (int ks = 0; ks < 4; ++ks) {
            bf8 kf[4];
#pragma unroll
            for (int nt = 0; nt < 4; ++nt)
                kf[nt] = *(const bf8*)(Kb + (ks >> 1) * 8192 + (nt * 16 + l15) * 128
                                       + (cswz ^ ((ks & 1) << 6)));
#pragma unroll
            for (int mt = 0; mt < 2; ++mt)
#pragma unroll
                for (int nt = 0; nt < 4; ++nt)
                    S[mt][nt] = __builtin_amdgcn_mfma_f32_16x16x32_bf16(qf[ks][mt], kf[nt], S[mt][nt], 0, 0, 0);
        }

        const bool domask = (kt >= 2 * qt);
#pragma unroll
        for (int mt = 0; mt < 2; ++mt)
#pragma unroll
            for (int r = 0; r < 4; ++r) {
                const int prow = w * 32 + mt * 16 + q4 * 4 + r;
                const int row = qt * 128 + prow;
                const int rsw = (prow & 7) << 4;
#pragma unroll
                for (int nt = 0; nt < 4; ++nt) {
                    float t = S[mt][nt][r] * cs;
                    if (domask && (kt * 64 + nt * 16 + l15 > row)) t = -1e30f;
                    float p = exp2f(t);
                    plrow[mt][r] += p;
                    *(u16*)(Pb + prow * 128 + ((((nt * 16 + l15) * 2)) ^ rsw)) = f2bf(p);
                }
            }

        // O += P V   (P rows are wave-private: no barrier needed)
#pragma unroll
        for (int pk = 0; pk < 2; ++pk) {
            bf8 pf[2], vf[8];
#pragma unroll
            for (int mt = 0; mt < 2; ++mt) {
                const int prow = w * 32 + mt * 16 + l15;
                pf[mt] = *(const bf8*)(Pb + prow * 128 + ((pk * 64 + q4 * 16) ^ ((l15 & 7) << 4)));
            }
#pragma unroll
            for (int nt = 0; nt < 8; ++nt)
                vf[nt] = *(const bf8*)(Vb + (nt * 16 + l15) * 128 + (cswz ^ (pk << 6)));
#pragma unroll
            for (int mt = 0; mt < 2; ++mt)
#pragma unroll
                for (int nt = 0; nt < 8; ++nt)
                    O[mt][nt] = __builtin_amdgcn_mfma_f32_16x16x32_bf16(pf[mt], vf[nt], O[mt][nt], 0, 0, 0);
        }
        // no trailing barrier: next iteration's top __syncthreads covers WAR
    }

#pragma unroll
    for (int mt = 0; mt < 2; ++mt)
#pragma unroll
        for (int r = 0; r < 4; ++r) {
            float ls = plrow[mt][r];   // row-sum lives across the 16 lanes of this q4 group
#pragma unroll
            for (int off = 1; off <= 8; off <<= 1)
                ls += __shfl_xor(ls, off, 64);
            const float linv = 1.0f / ls;
            const int row = qt * 128 + w * 32 + mt * 16 + q4 * 4 + r;
#pragma unroll
            for (int nt = 0; nt < 8; ++nt)
                aw[(size_t)row * 4096 + qh * HD + nt * 16 + l15] = f2bf(O[mt][nt][r] * linv);
        }
}

// ---------------- launch ----------------

extern "C" void kernel_launch(void* const* d_in, const int* in_sizes, int n_in,
                              void* d_out, int out_size, void* d_ws, size_t ws_size,
                              hipStream_t stream) {
    const float* hs = (const float*)d_in[0];
    const float* wqkv = (const float*)d_in[1];
    const float* wo = (const float*)d_in[2];
    float* out = (float*)d_out;

    char* ws = (char*)d_ws;
    const size_t oHbf = 0;
    const size_t oWqkvT = oHbf + (size_t)SEQ * HIDDEN * 2;          // 16.78 MB
    const size_t oWoT = oWqkvT + (size_t)DQKV * HIDDEN * 2;         // +50.33 MB
    const size_t oXQKV = oWoT + (size_t)HIDDEN * HIDDEN * 2;        // +33.55 MB
    const size_t oVT = oXQKV + (size_t)SEQ * DQKV * 2;              // +25.17 MB
    const size_t oAW = oVT + (size_t)8 * HD * SEQ * 2;              // +4.19 MB
    const size_t total = oAW + (size_t)SEQ * HIDDEN * 2;            // +16.78 MB = 146.8 MB
    if (ws_size < total) return;

    u16* Hbf = (u16*)(ws + oHbf);
    u16* WqkvT = (u16*)(ws + oWqkvT);
    u16* WoT = (u16*)(ws + oWoT);
    u16* XQKV = (u16*)(ws + oXQKV);
    u16* VT = (u16*)(ws + oVT);
    u16* AW = (u16*)(ws + oAW);

    // 5 kernels: fused prep, GEMM0, fused rope+tv, attn (dbuf), GEMM1
    prep_kernel<<<18432, 256, 0, stream>>>(hs, wqkv, wo, Hbf, WqkvT, WoT);
    gemm8p_kernel<256, 192, 0><<<256, 512, 0, stream>>>(Hbf, WqkvT, XQKV, nullptr);  // 8x32 grid
    rope_tv_kernel<<<20992, 256, 0, stream>>>(XQKV, VT);
    attn_kernel<<<512, 256, 0, stream>>>(XQKV, VT, AW);
    gemm8p_kernel<128, 256, 1><<<256, 512, 0, stream>>>(AW, WoT, nullptr, out);      // 16x16 grid
}